// Round 8
// baseline (456.479 us; speedup 1.0000x reference)
//
#include <hip/hip_runtime.h>
#include <cstdint>
#include <cstddef>

// Problem constants
#define NN 2048      // nodes
#define DM 512       // d_model
#define NH 8         // heads
#define HD 64        // head dim
#define NL 3         // layers
#define NE 32768     // edges

typedef unsigned short u16;
typedef unsigned int u32;
typedef __attribute__((ext_vector_type(8))) short short8;
typedef __attribute__((ext_vector_type(4))) float float4v;

__device__ __forceinline__ float bf2f(u16 s){
  union { unsigned u; float f; } v; v.u = ((unsigned)s) << 16; return v.f;
}
__device__ __forceinline__ u16 f2bf(float f){
  union { float f; unsigned u; } v; v.f = f;
  unsigned r = v.u + 0x7fffu + ((v.u >> 16) & 1u);
  return (u16)(r >> 16);
}
__device__ __forceinline__ u16 f2bf_fast(float f){
  union { float f; unsigned u; } v; v.f = f;
  return (u16)((v.u + 0x8000u) >> 16);
}
__device__ __forceinline__ void gl_lds16(const void* g, void* l){
  __builtin_amdgcn_global_load_lds((const __attribute__((address_space(1))) void*)g,
                                   (__attribute__((address_space(3))) void*)l, 16, 0, 0);
}

// ---------------- PE graph prep ----------------
__global__ void adj_scatter(const int* __restrict__ ei, float* __restrict__ A){
  int e = blockIdx.x*256 + threadIdx.x;
  if (e < NE){
    int s = ei[e], t = ei[NE + e];
    A[(size_t)s*NN + t] = 1.f;
    A[(size_t)t*NN + s] = 1.f;
  }
}

__global__ __launch_bounds__(256)
void rowsum_dinv(const float* __restrict__ A, float* __restrict__ dinv){
  int row = blockIdx.x, tid = threadIdx.x;
  __shared__ float red[4];
  float s = 0.f;
  for (int j=tid;j<NN;j+=256) s += A[(size_t)row*NN + j];
  #pragma unroll
  for (int off=32;off>0;off>>=1) s += __shfl_down(s, off);
  if ((tid&63)==0) red[tid>>6] = s;
  __syncthreads();
  if (tid==0) dinv[row] = rsqrtf(fmaxf(red[0]+red[1]+red[2]+red[3], 1.f));
}

// S row build + sparse extraction in one pass (S symmetric).
__global__ __launch_bounds__(256)
void build_s_nz(const float* __restrict__ A, const float* __restrict__ dinv,
                u16* __restrict__ S, u32* __restrict__ nz, int* __restrict__ cnt){
  const int i = blockIdx.x, tid = threadIdx.x;
  __shared__ int lc;
  if (tid==0) lc = 0;
  __syncthreads();
  const float di = dinv[i];
  for (int j=tid; j<NN; j+=256){
    float a = A[(size_t)i*NN + j];
    u16 v = f2bf(a * di * dinv[j]);
    S[(size_t)i*NN + j] = v;
    if (v){
      int s = atomicAdd(&lc, 1);
      if (s < 128) nz[i*128 + s] = ((u32)j << 16) | v;
    }
  }
  __syncthreads();
  if (tid==0) cnt[i] = lc < 128 ? lc : 128;
}

// S2 row j from nz-lists only (~33x33 LDS scatter-adds).
__global__ __launch_bounds__(256)
void spmm_sq(const u32* __restrict__ nz, const int* __restrict__ cnt,
             u16* __restrict__ S2)
{
  const int j = blockIdx.x, tid = threadIdx.x;
  __shared__ float row[2048];
  __shared__ u32 lnz[128];
  __shared__ int lcnt;
  for (int c=tid;c<2048;c+=256) row[c] = 0.f;
  if (tid==0) lcnt = cnt[j];
  if (tid<128) lnz[tid] = nz[j*128 + tid];
  __syncthreads();
  const int n = lcnt;
  const int g = tid >> 3, sub = tid & 7;
  for (int e = g; e < n; e += 32){
    u32 p = lnz[e];
    int k = p >> 16;
    float wv = bf2f((u16)(p & 0xffffu));
    int m = cnt[k];
    for (int f = sub; f < m; f += 8){
      u32 qq = nz[k*128 + f];
      atomicAdd(&row[qq >> 16], wv * bf2f((u16)(qq & 0xffffu)));
    }
  }
  __syncthreads();
  short8 o;
  #pragma unroll
  for (int t=0;t<8;t++) o[t] = (short)f2bf(row[tid*8 + t]);
  *(short8*)&S2[(size_t)j*NN + tid*8] = o;
}

// Bnew = S @ Bold via sparsity (row-gather; S symmetric).
__global__ __launch_bounds__(256)
void spmm(const u16* __restrict__ Bold, const u32* __restrict__ nz,
          const int* __restrict__ cnt, u16* __restrict__ Bnew)
{
  const int j = blockIdx.x, tid = threadIdx.x;
  __shared__ u32 lnz[128];
  __shared__ int lcnt;
  if (tid==0) lcnt = cnt[j];
  if (tid<128) lnz[tid] = nz[j*128 + tid];
  __syncthreads();
  const int n = lcnt;
  float acc[8] = {0,0,0,0,0,0,0,0};
  for (int e=0; e<n; e++){
    u32 p = lnz[e];
    int k = p >> 16;
    float wv = bf2f((u16)(p & 0xffffu));
    short8 rv = *(const short8*)&Bold[(size_t)k*NN + tid*8];
    #pragma unroll
    for (int t=0;t<8;t++) acc[t] = fmaf(bf2f((u16)rv[t]), wv, acc[t]);
  }
  short8 o;
  #pragma unroll
  for (int t=0;t<8;t++) o[t] = (short)f2bf(acc[t]);
  *(short8*)&Bnew[(size_t)j*NN + tid*8] = o;
}

// diag(T^k)=diag(S^k); fused pe_proj + per-layer head projection.
__global__ __launch_bounds__(256)
void diag_pe(const u16* __restrict__ S, const u16* __restrict__ S2,
             const u16* __restrict__ S3, const u16* __restrict__ S4,
             const float* __restrict__ peW, const float* __restrict__ peb,
             const float* __restrict__ pebW, const float* __restrict__ pebb,
             float* __restrict__ pebT)
{
  const int i = blockIdx.x, tid = threadIdx.x;
  float d[7] = {0,0,0,0,0,0,0};
  for (int j=tid;j<NN;j+=256){
    float s1 = bf2f(S [(size_t)i*NN + j]);
    float s2 = bf2f(S2[(size_t)i*NN + j]);
    float s3 = bf2f(S3[(size_t)i*NN + j]);
    float s4 = bf2f(S4[(size_t)i*NN + j]);
    d[0] += s1*s1; d[1] += s1*s2; d[2] += s2*s2; d[3] += s2*s3;
    d[4] += s3*s3; d[5] += s3*s4; d[6] += s4*s4;
  }
  __shared__ float red[28];
  __shared__ float pv[16];
  #pragma unroll
  for (int t=0;t<7;t++){
    float v = d[t];
    #pragma unroll
    for (int off=32;off>0;off>>=1) v += __shfl_down(v, off);
    if ((tid&63)==0) red[t*4 + (tid>>6)] = v;
  }
  __syncthreads();
  if (tid < 16){
    float rr[8];
    rr[0] = bf2f(S[(size_t)i*NN + i]);
    #pragma unroll
    for (int t=0;t<7;t++) rr[t+1] = red[t*4]+red[t*4+1]+red[t*4+2]+red[t*4+3];
    float a = peb[tid];
    #pragma unroll
    for (int k=0;k<8;k++) a += rr[k]*peW[k*16 + tid];
    pv[tid] = a;
  }
  __syncthreads();
  if (tid < 24){
    int l = tid >> 3, h = tid & 7;
    float a = pebb[l*NH + h];
    #pragma unroll
    for (int p=0;p<16;p++) a += pv[p]*pebW[(l*16+p)*NH + h];
    pebT[((size_t)l*NH + h)*NN + i] = a;
  }
}

// ---------------- misc ----------------
__global__ void init_x(const float* __restrict__ nf, float* __restrict__ x, u16* __restrict__ xbf){
  size_t i = (size_t)blockIdx.x*256 + threadIdx.x;
  float v = nf[i]; x[i] = v; xbf[i] = f2bf(v);
}

// all weight transposes (f32 [K][N] -> bf16 [N][K], 3 layers) in ONE kernel.
__global__ __launch_bounds__(256)
void transpose_all(const float* __restrict__ qkvW, const float* __restrict__ outW,
                   const float* __restrict__ f1W,  const float* __restrict__ f2W,
                   u16* __restrict__ qkvT, u16* __restrict__ outT,
                   u16* __restrict__ f1T,  u16* __restrict__ f2T)
{
  __shared__ float t[32][33];
  int gid = blockIdx.x;
  int l = gid / 3072, r = gid % 3072;
  const float* W; u16* WT; int K, N, bx, by;
  if (r < 768)      { W=qkvW; WT=qkvT; K=512;  N=1536; bx=r%48;        by=r/48; }
  else if (r < 1024){ int u=r-768;  W=outW; WT=outT; K=512;  N=512;  bx=u%16; by=u/16; }
  else if (r < 2048){ int u=r-1024; W=f1W;  WT=f1T;  K=512;  N=2048; bx=u%64; by=u/64; }
  else              { int u=r-2048; W=f2W;  WT=f2T;  K=2048; N=512;  bx=u%16; by=u/16; }
  W  += (size_t)l*K*N;
  WT += (size_t)l*K*N;
  int n0 = bx*32, k0 = by*32;
  int tx = threadIdx.x & 31, ty = threadIdx.x >> 5;
  #pragma unroll
  for (int i=0;i<32;i+=8) t[ty+i][tx] = W[(size_t)(k0+ty+i)*N + n0+tx];
  __syncthreads();
  #pragma unroll
  for (int i=0;i<32;i+=8) WT[(size_t)(n0+ty+i)*K + k0+tx] = f2bf(t[tx][ty+i]);
}

// LayerNorm(x + sum_{s<nsl} f32 slices) -> xout (f32) and xbf (bf16).
__global__ __launch_bounds__(256)
void ln_kernel(const float* __restrict__ xin, const float* __restrict__ add, int nsl,
               const float* __restrict__ g, const float* __restrict__ b,
               float* __restrict__ xout, u16* __restrict__ xbf)
{
  const int row = blockIdx.x, tid = threadIdx.x;
  __shared__ float red[8];
  const size_t base = (size_t)row*DM;
  float v0 = xin[base+tid];
  float v1 = xin[base+256+tid];
  for (int s=0;s<nsl;s++){
    v0 += add[(size_t)s*NN*DM + base+tid];
    v1 += add[(size_t)s*NN*DM + base+256+tid];
  }
  float s = v0+v1, sq = v0*v0 + v1*v1;
  #pragma unroll
  for (int off=32; off>0; off>>=1){ s += __shfl_down(s, off); sq += __shfl_down(sq, off); }
  if ((tid&63)==0){ red[tid>>6] = s; red[4+(tid>>6)] = sq; }
  __syncthreads();
  float mean = (red[0]+red[1]+red[2]+red[3]) * (1.f/512.f);
  float var  = (red[4]+red[5]+red[6]+red[7]) * (1.f/512.f) - mean*mean;
  float rstd = rsqrtf(var + 1e-5f);
  float y0 = (v0-mean)*rstd*g[tid]     + b[tid];
  float y1 = (v1-mean)*rstd*g[256+tid] + b[256+tid];
  xout[base+tid] = y0;     xout[base+256+tid] = y1;
  xbf[base+tid]  = f2bf(y0); xbf[base+256+tid] = f2bf(y1);
}

// ------- 32x64-tile GEMM body, BK=64, dbuf, XOR-swizzled LDS -------
// Small tiles -> 4-8 blocks/CU so the barrier's vmcnt(0) drain (un-fixable at
// HIP level) is overlapped by many co-resident waves. Waves: 2x2 grid, each
// wave owns m16 x n32 (2 n-tiles).
// ACOMB=1: A-tile is built in-regs from 4 attn key-split partials (bf16) x
// 1/L (from Lsum) -- folds attn_combine into this GEMM; iter it == head.
template<int OUTMODE, int GELU, int BIAS, int ACOMB>
__device__ __forceinline__ void gemm32_body(
    u16* As, u16* Bs, float* invLs,
    const u16* __restrict__ A, const u16* __restrict__ BT,
    const float* __restrict__ bias, void* __restrict__ Cout,
    const u16* __restrict__ Opart, const float* __restrict__ Lsum,
    int M, int N, int K, int ldc, int kper, int bm, int bn, int bz)
{
  const int tid = threadIdx.x, lane = tid & 63, wave = tid >> 6;
  const int q = lane >> 4, lo = lane & 15;
  const int wm = wave >> 1, wn = wave & 1;
  const int k_begin = bz * kper;
  const int kiters = kper >> 6;
  const int srow   = lane >> 3;
  const int gchunk = (lane & 7) ^ srow;

  // B staging: each wave stages 16 rows in 2 rounds of 8.
  const u16* Bg = BT + ((size_t)bn*64 + 16*wave + srow) * (size_t)K + k_begin + gchunk*8;
  const size_t r8 = (size_t)8 * K;
  const int Bwoff = wave * 1024;

  // A staging (non-ACOMB): each wave stages 8 rows.
  const u16* Ag = nullptr;
  const int Awoff = wave * 512;
  if (!ACOMB)
    Ag = A + ((size_t)bm*32 + wave*8 + srow) * (size_t)K + k_begin + gchunk*8;

  // ACOMB setup: per-(row,head) 1/L and per-thread staging coords.
  int c_sr=0, c_gc=0, c_qb=0, c_rr=0;
  if (ACOMB){
    c_sr = tid >> 3; c_gc = tid & 7;
    c_qb = bm >> 2; c_rr = (bm & 3)*32 + c_sr;
    int hh = tid & 7, rr2 = (bm & 3)*32 + (tid >> 3);
    float L = 0.f;
    #pragma unroll
    for (int ks=0;ks<4;ks++)
      L += Lsum[(((ks*NH + hh)*16 + c_qb))*128 + rr2];
    invLs[(tid>>3)*8 + hh] = 1.f / L;
    __syncthreads();
  }

  float4v acc[2] = {};

  // stage iter 0
  if (ACOMB){
    const int h0 = bz * kiters;
    float a8[8] = {0,0,0,0,0,0,0,0};
    #pragma unroll
    for (int ks=0;ks<4;ks++){
      short8 p = *(const short8*)&Opart[((size_t)((ks*NH + h0)*16 + c_qb))*8192 + c_rr*64 + c_gc*8];
      #pragma unroll
      for (int t=0;t<8;t++) a8[t] += bf2f((u16)p[t]);
    }
    float il = invLs[c_sr*8 + h0 - bz*kiters*0]; // invLs indexed by head
    il = invLs[c_sr*8 + (h0 & 7)];
    short8 o;
    #pragma unroll
    for (int t=0;t<8;t++) o[t] = (short)f2bf_fast(a8[t]*il);
    *(short8*)&As[c_sr*64 + ((c_gc ^ (c_sr&7))*8)] = o;
  } else {
    gl_lds16(Ag, As + Awoff);
  }
  gl_lds16(Bg,      Bs + Bwoff);
  gl_lds16(Bg + r8, Bs + Bwoff + 512);

  for (int it = 0; it < kiters; ++it){
    const int curA = (it & 1) << 11, nxtA = curA ^ 2048;
    const int curB = (it & 1) << 12, nxtB = curB ^ 4096;
    __syncthreads();
    if (it + 1 < kiters){
      const int ko = (it+1)*64;
      if (ACOMB){
        const int h = bz*kiters + it + 1;
        float a8[8] = {0,0,0,0,0,0,0,0};
        #pragma unroll
        for (int ks=0;ks<4;ks++){
          short8 p = *(const short8*)&Opart[((size_t)((ks*NH + h)*16 + c_qb))*8192 + c_rr*64 + c_gc*8];
          #pragma unroll
          for (int t=0;t<8;t++) a8[t] += bf2f((u16)p[t]);
        }
        float il = invLs[c_sr*8 + (h & 7)];
        short8 o;
        #pragma unroll
        for (int t=0;t<8;t++) o[t] = (short)f2bf_fast(a8[t]*il);
        *(short8*)&As[nxtA + c_sr*64 + ((c_gc ^ (c_sr&7))*8)] = o;
      } else {
        gl_lds16(Ag + ko, As + nxtA + Awoff);
      }
      gl_lds16(Bg + ko,      Bs + nxtB + Bwoff);
      gl_lds16(Bg + ko + r8, Bs + nxtB + Bwoff + 512);
    }
    const short8* Ar = (const short8*)(As + curA);
    const short8* Br = (const short8*)(Bs + curB);
    #pragma unroll
    for (int kk=0;kk<2;kk++){
      const int cx = (kk*4 + q) ^ (lo & 7);
      short8 af = Ar[(16*wm + lo)*8 + cx];
      #pragma unroll
      for (int nt=0;nt<2;nt++){
        short8 bfr = Br[(32*wn + 16*nt + lo)*8 + cx];
        acc[nt] = __builtin_amdgcn_mfma_f32_16x16x32_bf16(af, bfr, acc[nt], 0, 0, 0);
      }
    }
  }

  float* Cf = (float*)Cout;
  u16*   Cb = (u16*)Cout;
  const size_t zoff = (OUTMODE == 2) ? (size_t)bz * M * ldc : 0;
  const int row = bm*32 + 16*wm + q*4;
  #pragma unroll
  for (int nt=0;nt<2;nt++){
    const int col = bn*64 + 32*wn + 16*nt + lo;
    float bbc = (BIAS==1) ? bias[col] : 0.f;
    #pragma unroll
    for (int r=0;r<4;r++){
      float v = acc[nt][r];
      float bb = (BIAS==2) ? bias[row+r] : bbc;
      if (OUTMODE == 2){
        if (BIAS && bz == 0) v += bb;
        Cf[zoff + (size_t)(row+r)*ldc + col] = v;
      } else {
        v += bb;
        if (GELU) v = 0.5f*v*(1.f + erff(v*0.70710678118654752f));
        if (OUTMODE == 1) Cb[(size_t)(row+r)*ldc + col] = f2bf(v);
        else              Cf[(size_t)(row+r)*ldc + col] = v;
      }
    }
  }
}

template<int OUTMODE, int GELU, int BIAS>
__global__ __launch_bounds__(256)
void gemm32(const u16* __restrict__ A, const u16* __restrict__ BT,
            const float* __restrict__ bias, void* __restrict__ Cout,
            int M, int N, int K, int ldc, int kper)
{
  __shared__ u16 As[2*2048];
  __shared__ u16 Bs[2*4096];
  __shared__ float invLs[256];
  gemm32_body<OUTMODE,GELU,BIAS,0>(As, Bs, invLs, A, BT, bias, Cout, nullptr, nullptr,
                                   M, N, K, ldc, kper, blockIdx.y, blockIdx.x, blockIdx.z);
}

// qk GEMM (1024 tasks) + vT GEMM (512 tasks) in one 1536-block dispatch.
__global__ __launch_bounds__(256)
void qkvt_fused(const u16* __restrict__ xbf, const u16* __restrict__ qkT,
                const float* __restrict__ qkb, u16* __restrict__ qkB,
                const u16* __restrict__ vwT, const float* __restrict__ vb,
                u16* __restrict__ vT)
{
  __shared__ u16 As[2*2048];
  __shared__ u16 Bs[2*4096];
  __shared__ float invLs[256];
  int id = blockIdx.x;
  if (id < 1024)
    gemm32_body<1,0,1,0>(As, Bs, invLs, xbf, qkT, qkb, qkB, nullptr, nullptr,
                         2048, 1024, 512, 1024, 512, id >> 4, id & 15, 0);
  else {
    id -= 1024;
    gemm32_body<1,0,2,0>(As, Bs, invLs, vwT, xbf, vb, vT, nullptr, nullptr,
                         512, 2048, 512, 2048, 512, id >> 5, id & 31, 0);
  }
}

// out-proj with fused attn-combine A-staging. grid (8 n, 64 m, 2 z).
__global__ __launch_bounds__(256)
void outproj_comb(const u16* __restrict__ Opart, const float* __restrict__ Lsum,
                  const u16* __restrict__ outT, const float* __restrict__ outb,
                  float* __restrict__ Cslices)
{
  __shared__ u16 As[2*2048];
  __shared__ u16 Bs[2*4096];
  __shared__ float invLs[256];
  gemm32_body<2,0,1,1>(As, Bs, invLs, nullptr, outT, outb, Cslices, Opart, Lsum,
                       2048, 512, 512, 512, 256, blockIdx.y, blockIdx.x, blockIdx.z);
}

// ------- fused flash attention, Q-tile 128, key-split 4x, dbuf K/V -------
// Row-bias cancels in softmax; scores bounded -> single-pass exp2 softmax.
// Partial O written as bf16 (plain sums; no max rescale needed).
__global__ __launch_bounds__(256)
void attn_part(const u16* __restrict__ qkB, const u16* __restrict__ vT,
               const float* __restrict__ pebT, u16* __restrict__ Opart,
               float* __restrict__ Lsum)
{
  __shared__ u16 Ks[2][64*72];
  __shared__ u16 Vs[2][64*72];
  __shared__ u16 Ps[128*72];
  __shared__ float CB[2][64];
  const int tid = threadIdx.x, lane = tid&63, wave = tid>>6;
  const int q = lane>>4, lo = lane&15;
  const int qb = blockIdx.x, h = blockIdx.y, ks = blockIdx.z;
  const int i0 = qb*128;
  const int part = (ks*NH + h)*16 + qb;

  short8 qf[2][2];
  #pragma unroll
  for (int mt=0;mt<2;mt++)
    #pragma unroll
    for (int kk=0;kk<2;kk++)
      qf[kk][mt] = *(const short8*)&qkB[(size_t)(i0 + 32*wave + 16*mt + lo)*1024 + h*64 + kk*32 + q*8];

  float l_r[2][4] = {};
  float4v o_acc[2][4] = {};

  const int srow = tid >> 2, soff = (tid & 3) * 16;
  const int j_begin = ks*512, j_end = j_begin + 512;

  {
    float4v k0a = *(const float4v*)&qkB[(size_t)(j_begin+srow)*1024 + 512 + h*64 + soff];
    float4v k0b = *(const float4v*)&qkB[(size_t)(j_begin+srow)*1024 + 512 + h*64 + soff + 8];
    float4v v0a = *(const float4v*)&vT[(size_t)(h*64+srow)*NN + j_begin + soff];
    float4v v0b = *(const float4v*)&vT[(size_t)(h*64+srow)*NN + j_begin + soff + 8];
    *(float4v*)&Ks[0][srow*72 + soff]     = k0a;
    *(float4v*)&Ks[0][srow*72 + soff + 8] = k0b;
    *(float4v*)&Vs[0][srow*72 + soff]     = v0a;
    *(float4v*)&Vs[0][srow*72 + soff + 8] = v0b;
    if (tid < 64) CB[0][tid] = pebT[(size_t)h*NN + j_begin + tid] * 1.4426950408889634f;
  }
  __syncthreads();

  for (int j0 = j_begin; j0 < j_end; j0 += 64){
    const int cur = ((j0 - j_begin) >> 6) & 1, nxt = cur ^ 1;
    const bool has_next = (j0 + 64 < j_end);
    float4v ka, kb, va, vb; float cbr = 0.f;
    if (has_next){
      ka = *(const float4v*)&qkB[(size_t)(j0+64+srow)*1024 + 512 + h*64 + soff];
      kb = *(const float4v*)&qkB[(size_t)(j0+64+srow)*1024 + 512 + h*64 + soff + 8];
      va = *(const float4v*)&vT[(size_t)(h*64+srow)*NN + j0+64 + soff];
      vb = *(const float4v*)&vT[(size_t)(h*64+srow)*NN + j0+64 + soff + 8];
      if (tid < 64) cbr = pebT[(size_t)h*NN + j0+64 + tid] * 1.4426950408889634f;
    }

    float4v sacc[2][4] = {};
    const short8* Kr = (const short8*)Ks[cur];
    #pragma unroll
    for (int kk=0; kk<2; kk++){
      #pragma unroll
      for (int nt=0; nt<4; nt++){
        short8 bfr = Kr[(16*nt + lo)*9 + kk*4 + q];
        #pragma unroll
        for (int mt=0; mt<2; mt++)
          sacc[mt][nt] = __builtin_amdgcn_mfma_f32_16x16x32_bf16(qf[kk][mt], bfr, sacc[mt][nt], 0,0,0);
      }
    }
    #pragma unroll
    for (int mt=0; mt<2; mt++)
      #pragma unroll
      for (int nt=0; nt<4; nt++){
        float cb = CB[cur][16*nt + lo];
        #pragma unroll
        for (int r=0;r<4;r++){
          float p = exp2f(fmaf(sacc[mt][nt][r], 0.180336880f, -cb));
          l_r[mt][r] += p;
          Ps[(32*wave + 16*mt + q*4 + r)*72 + 16*nt + lo] = f2bf_fast(p);
        }
      }
    const short8* Pr = (const short8*)Ps;
    const short8* Vr = (const short8*)Vs[cur];
    #pragma unroll
    for (int kk=0;kk<2;kk++){
      #pragma unroll
      for (int mt=0;mt<2;mt++){
        short8 af = Pr[(32*wave + 16*mt + lo)*9 + kk*4 + q];
        #pragma unroll
        for (int nt=0;nt<4;nt++){
          short8 bfr = Vr[(16*nt + lo)*9 + kk*4 + q];
          o_acc[mt][nt] = __builtin_amdgcn_mfma_f32_16x16x32_bf16(af, bfr, o_acc[mt][nt], 0,0,0);
        }
      }
    }
    if (has_next){
      *(float4v*)&Ks[nxt][srow*72 + soff]     = ka;
      *(float4v*)&Ks[nxt][srow*72 + soff + 8] = kb;
      *(float4v*)&Vs[nxt][srow*72 + soff]     = va;
      *(float4v*)&Vs[nxt][srow*72 + soff + 8] = vb;
      if (tid < 64) CB[nxt][tid] = cbr;
    }
    __syncthreads();
  }

  u16* Op = Opart + (size_t)part*8192; // bf16 [128][64]
  #pragma unroll
  for (int mt=0;mt<2;mt++){
    #pragma unroll
    for (int r=0;r<4;r++){
      float s = l_r[mt][r];
      s += __shfl_xor(s, 1);
      s += __shfl_xor(s, 2);
      s += __shfl_xor(s, 4);
      s += __shfl_xor(s, 8);
      if (lo == 0) Lsum[part*128 + 32*wave + 16*mt + q*4 + r] = s;
    }
    #pragma unroll
    for (int nt=0;nt<4;nt++)
      #pragma unroll
      for (int r=0;r<4;r++)
        Op[(32*wave + 16*mt + q*4 + r)*64 + 16*nt + lo] = f2bf_fast(o_acc[mt][nt][r]);
  }
}

// ---------------- launch ----------------
extern "C" void kernel_launch(void* const* d_in, const int* in_sizes, int n_in,
                              void* d_out, int out_size, void* d_ws, size_t ws_size,
                              hipStream_t stream) {
  const float* nf   = (const float*)d_in[0];
  const int*   ei   = (const int*)d_in[1];
  const float* peW  = (const float*)d_in[2];
  const float* peb  = (const float*)d_in[3];
  const float* qkvW = (const float*)d_in[4];
  const float* qkvb = (const float*)d_in[5];
  const float* pebW = (const float*)d_in[6];
  const float* pebb = (const float*)d_in[7];
  const float* outW = (const float*)d_in[8];
  const float* outb = (const float*)d_in[9];
  const float* f1W  = (const float*)d_in[10];
  const float* f1b  = (const float*)d_in[11];
  const float* f2W  = (const float*)d_in[12];
  const float* f2b  = (const float*)d_in[13];
  const float* ln1g = (const float*)d_in[14];
  const float* ln1b = (const float*)d_in[15];
  const float* ln2g = (const float*)d_in[16];
  const float* ln2b = (const float*)d_in[17];
  (void)in_sizes; (void)n_in; (void)out_size; (void)ws_size;

  char* w = (char*)d_ws;
  // A (16.78 MB): adjacency -> [Opart bf16 8.4MB | outproj f32 slices 8.4MB]
  // -> ffn2 f32 slices (first 8.4MB).
  constexpr size_t OFF_A     = 0;
  constexpr size_t OFF_S     = OFF_A + 16777216;
  constexpr size_t OFF_S2    = OFF_S + 8388608;
  constexpr size_t OFF_S3    = OFF_S2 + 8388608;
  constexpr size_t OFF_S4    = OFF_S3 + 8388608;
  constexpr size_t OFF_DINV  = OFF_S4 + 8388608;
  constexpr size_t OFF_PEBT  = OFF_DINV + 8192;
  constexpr size_t OFF_QKVT  = OFF_PEBT + 196608;
  constexpr size_t OFF_OUTT  = OFF_QKVT + 4718592;
  constexpr size_t OFF_F1T   = OFF_OUTT + 1572864;
  constexpr size_t OFF_F2T   = OFF_F1T + 6291456;
  constexpr size_t OFF_X     = OFF_F2T + 6291456;
  constexpr size_t OFF_XBF   = OFF_X + 4194304;
  constexpr size_t OFF_QKB   = OFF_XBF + 2097152;
  constexpr size_t OFF_VT    = OFF_QKB + 4194304;
  constexpr size_t OFF_NZ    = OFF_VT + 2097152;
  constexpr size_t OFF_CNT   = OFF_NZ + 1048576;
  constexpr size_t OFF_LS    = OFF_CNT + 8192;
  constexpr size_t OFF_HBUF  = OFF_LS + 262144;

  float* A     = (float*)(w + OFF_A);
  u16*   S     = (u16*)  (w + OFF_S);
  u16*   S2    = (u16*)  (w + OFF_S2);
  u16*   S3    = (u16*)  (w + OFF_S3);
  u16*   S4    = (u16*)  (w + OFF_S4);
  float* dinv  = (float*)(w + OFF_DINV);
  float* pebT  = (float*)(w + OFF_PEBT);
  u16*   qkvT  = (u16*)  (w + OFF_QKVT);
  u16*   outT  = (u16*)  (w + OFF_OUTT);
  u16*   f1T   = (u16*)  (w + OFF_F1T);
  u16*   f2T   = (u16*)  (w + OFF_F2T);
  float* x     = (float*)(w + OFF_X);
  u16*   xbf   = (u16*)  (w + OFF_XBF);
  u16*   qkB   = (u16*)  (w + OFF_QKB);
  u16*   vT    = (u16*)  (w + OFF_VT);
  u32*   NZ    = (u32*)  (w + OFF_NZ);
  int*   CNT   = (int*)  (w + OFF_CNT);
  float* Lsum  = (float*)(w + OFF_LS);
  u16*   hbuf  = (u16*)  (w + OFF_HBUF);
  u16*   Opart   = (u16*)A;                        // 8.4 MB
  float* Oslices = (float*)(w + OFF_A + 8388608);  // 2 x 4.2 MB f32
  float* Fslices = (float*)A;                      // 2 x 4.2 MB f32 (Opart dead)

  // ---- PE path (S sparse: ~33 nnz/row) ----
  hipMemsetAsync(A, 0, 16777216, stream);
  adj_scatter<<<dim3(NE/256), 256, 0, stream>>>(ei, A);
  rowsum_dinv<<<dim3(NN), 256, 0, stream>>>(A, dinv);
  build_s_nz<<<dim3(NN), 256, 0, stream>>>(A, dinv, S, NZ, CNT);
  spmm_sq<<<dim3(NN), 256, 0, stream>>>(NZ, CNT, S2);
  spmm<<<dim3(NN), 256, 0, stream>>>(S2, NZ, CNT, S3);
  spmm<<<dim3(NN), 256, 0, stream>>>(S3, NZ, CNT, S4);
  diag_pe<<<dim3(NN), 256, 0, stream>>>(S, S2, S3, S4, peW, peb, pebW, pebb, pebT);

  transpose_all<<<dim3(9216), 256, 0, stream>>>(qkvW, outW, f1W, f2W, qkvT, outT, f1T, f2T);
  init_x<<<dim3(NN*DM/256), 256, 0, stream>>>(nf, x, xbf);

  // ---- transformer layers ----
  for (int l = 0; l < NL; l++){
    qkvt_fused<<<dim3(1536), 256, 0, stream>>>(
        xbf, qkvT + (size_t)l*1536*512, qkvb + l*1536, qkB,
        qkvT + (size_t)l*1536*512 + (size_t)1024*512, qkvb + l*1536 + 1024, vT);
    attn_part<<<dim3(16,8,4), 256, 0, stream>>>(qkB, vT, pebT + (size_t)l*NH*NN, Opart, Lsum);

    outproj_comb<<<dim3(8,64,2), 256, 0, stream>>>(
        Opart, Lsum, outT + (size_t)l*512*512, outb + l*512, Oslices);
    ln_kernel<<<dim3(NN), 256, 0, stream>>>(x, Oslices, 2, ln1g + l*512, ln1b + l*512, x, xbf);

    gemm32<1,1,1><<<dim3(32,64,1), 256, 0, stream>>>(
        xbf, f1T + (size_t)l*2048*512, f1b + l*2048, hbuf, 2048, 2048, 512, 2048, 512);
    gemm32<2,0,1><<<dim3(8,64,2), 256, 0, stream>>>(
        hbuf, f2T + (size_t)l*512*2048, f2b + l*512, Fslices, 2048, 512, 2048, 512, 1024);
    float* xout = (l == NL-1) ? (float*)d_out : x;
    ln_kernel<<<dim3(NN), 256, 0, stream>>>(x, Fslices, 2, ln2g + l*512, ln2b + l*512, xout, xbf);
  }
}

// Round 9
// 435.707 us; speedup vs baseline: 1.0477x; 1.0477x over previous
//
#include <hip/hip_runtime.h>
#include <cstdint>
#include <cstddef>

// Problem constants
#define NN 2048      // nodes
#define DM 512       // d_model
#define NH 8         // heads
#define HD 64        // head dim
#define NL 3         // layers
#define NE 32768     // edges

typedef unsigned short u16;
typedef unsigned int u32;
typedef __attribute__((ext_vector_type(8))) short short8;
typedef __attribute__((ext_vector_type(4))) float float4v;

__device__ __forceinline__ float bf2f(u16 s){
  union { unsigned u; float f; } v; v.u = ((unsigned)s) << 16; return v.f;
}
__device__ __forceinline__ u16 f2bf(float f){
  union { float f; unsigned u; } v; v.f = f;
  unsigned r = v.u + 0x7fffu + ((v.u >> 16) & 1u);
  return (u16)(r >> 16);
}
__device__ __forceinline__ u16 f2bf_fast(float f){
  union { float f; unsigned u; } v; v.f = f;
  return (u16)((v.u + 0x8000u) >> 16);
}
__device__ __forceinline__ void gl_lds16(const void* g, void* l){
  __builtin_amdgcn_global_load_lds((const __attribute__((address_space(1))) void*)g,
                                   (__attribute__((address_space(3))) void*)l, 16, 0, 0);
}

// ---------------- PE graph prep ----------------
__global__ void adj_scatter(const int* __restrict__ ei, float* __restrict__ A){
  int e = blockIdx.x*256 + threadIdx.x;
  if (e < NE){
    int s = ei[e], t = ei[NE + e];
    A[(size_t)s*NN + t] = 1.f;
    A[(size_t)t*NN + s] = 1.f;
  }
}

__global__ __launch_bounds__(256)
void rowsum_dinv(const float* __restrict__ A, float* __restrict__ dinv){
  int row = blockIdx.x, tid = threadIdx.x;
  __shared__ float red[4];
  float s = 0.f;
  for (int j=tid;j<NN;j+=256) s += A[(size_t)row*NN + j];
  #pragma unroll
  for (int off=32;off>0;off>>=1) s += __shfl_down(s, off);
  if ((tid&63)==0) red[tid>>6] = s;
  __syncthreads();
  if (tid==0) dinv[row] = rsqrtf(fmaxf(red[0]+red[1]+red[2]+red[3], 1.f));
}

// S row build + sparse extraction in one pass (S symmetric).
__global__ __launch_bounds__(256)
void build_s_nz(const float* __restrict__ A, const float* __restrict__ dinv,
                u16* __restrict__ S, u32* __restrict__ nz, int* __restrict__ cnt){
  const int i = blockIdx.x, tid = threadIdx.x;
  __shared__ int lc;
  if (tid==0) lc = 0;
  __syncthreads();
  const float di = dinv[i];
  for (int j=tid; j<NN; j+=256){
    float a = A[(size_t)i*NN + j];
    u16 v = f2bf(a * di * dinv[j]);
    S[(size_t)i*NN + j] = v;
    if (v){
      int s = atomicAdd(&lc, 1);
      if (s < 128) nz[i*128 + s] = ((u32)j << 16) | v;
    }
  }
  __syncthreads();
  if (tid==0) cnt[i] = lc < 128 ? lc : 128;
}

// ------- fused prep: spmm_sq(+k1..k4) | transpose_all | init_x -------
// blocks 0..2047: S2 row j from nz-lists + diag dots k1..k4
// blocks 2048..11263: weight transposes (f32 [K][N] -> bf16 [N][K])
// blocks 11264..15359: init x/xbf from node_features
__global__ __launch_bounds__(256)
void fused_prep(const u32* __restrict__ nz, const int* __restrict__ cnt,
                const u16* __restrict__ S, u16* __restrict__ S2, float* __restrict__ diagsG,
                const float* __restrict__ qkvW, const float* __restrict__ outW,
                const float* __restrict__ f1W,  const float* __restrict__ f2W,
                u16* __restrict__ qkvT, u16* __restrict__ outT,
                u16* __restrict__ f1T,  u16* __restrict__ f2T,
                const float* __restrict__ nf, float* __restrict__ x, u16* __restrict__ xbf)
{
  __shared__ __align__(16) char sm[8960];
  const int bid = blockIdx.x, tid = threadIdx.x;
  if (bid < 2048){
    float* row  = (float*)sm;           // 2048 f32
    u32*   lnz  = (u32*)(sm + 8192);    // 128
    int*   lcnt = (int*)(sm + 8704);
    float* rbuf = (float*)(sm + 8708);  // 12
    const int j = bid;
    for (int c=tid;c<2048;c+=256) row[c] = 0.f;
    if (tid==0) *lcnt = cnt[j];
    if (tid<128) lnz[tid] = nz[j*128 + tid];
    __syncthreads();
    const int n = *lcnt;
    const int g = tid >> 3, sub = tid & 7;
    for (int e = g; e < n; e += 32){
      u32 p = lnz[e];
      int k = p >> 16;
      float wv = bf2f((u16)(p & 0xffffu));
      int m = cnt[k];
      for (int f = sub; f < m; f += 8){
        u32 qq = nz[k*128 + f];
        atomicAdd(&row[qq >> 16], wv * bf2f((u16)(qq & 0xffffu)));
      }
    }
    __syncthreads();
    short8 sv = *(const short8*)&S[(size_t)j*NN + tid*8];
    short8 o; float k2=0.f,k3=0.f,k4=0.f;
    #pragma unroll
    for (int t=0;t<8;t++){
      float s2v = row[tid*8 + t], s1v = bf2f((u16)sv[t]);
      o[t] = (short)f2bf(s2v);
      k2 += s1v*s1v; k3 += s1v*s2v; k4 += s2v*s2v;
    }
    *(short8*)&S2[(size_t)j*NN + tid*8] = o;
    #pragma unroll
    for (int off=32;off>0;off>>=1){
      k2 += __shfl_down(k2,off); k3 += __shfl_down(k3,off); k4 += __shfl_down(k4,off);
    }
    if ((tid&63)==0){ int wv_ = tid>>6; rbuf[wv_]=k2; rbuf[4+wv_]=k3; rbuf[8+wv_]=k4; }
    __syncthreads();
    if (tid==0){
      diagsG[j*8+0] = bf2f(S[(size_t)j*NN + j]);
      diagsG[j*8+1] = rbuf[0]+rbuf[1]+rbuf[2]+rbuf[3];
      diagsG[j*8+2] = rbuf[4]+rbuf[5]+rbuf[6]+rbuf[7];
      diagsG[j*8+3] = rbuf[8]+rbuf[9]+rbuf[10]+rbuf[11];
    }
  } else if (bid < 2048 + 9216){
    float (*t)[33] = (float(*)[33])sm;
    int gid = bid - 2048;
    int l = gid / 3072, r = gid % 3072;
    const float* W; u16* WT; int K, N, bx, by;
    if (r < 768)      { W=qkvW; WT=qkvT; K=512;  N=1536; bx=r%48;        by=r/48; }
    else if (r < 1024){ int u=r-768;  W=outW; WT=outT; K=512;  N=512;  bx=u%16; by=u/16; }
    else if (r < 2048){ int u=r-1024; W=f1W;  WT=f1T;  K=512;  N=2048; bx=u%64; by=u/64; }
    else              { int u=r-2048; W=f2W;  WT=f2T;  K=2048; N=512;  bx=u%16; by=u/16; }
    W  += (size_t)l*K*N;
    WT += (size_t)l*K*N;
    int n0 = bx*32, k0 = by*32;
    int tx = tid & 31, ty = tid >> 5;
    #pragma unroll
    for (int i=0;i<32;i+=8) t[ty+i][tx] = W[(size_t)(k0+ty+i)*N + n0+tx];
    __syncthreads();
    #pragma unroll
    for (int i=0;i<32;i+=8) WT[(size_t)(n0+ty+i)*K + k0+tx] = f2bf(t[tx][ty+i]);
  } else {
    size_t i = (size_t)(bid - 11264)*256 + tid;
    float v = nf[i]; x[i] = v; xbf[i] = f2bf(v);
  }
}

// S3 = S @ S2 (row-gather) + k5,k6 diag dots.
__global__ __launch_bounds__(256)
void spmm_d34(const u16* __restrict__ S2, const u32* __restrict__ nz,
              const int* __restrict__ cnt, u16* __restrict__ S3, float* __restrict__ diagsG)
{
  const int j = blockIdx.x, tid = threadIdx.x;
  __shared__ u32 lnz[128];
  __shared__ int lcnt;
  __shared__ float rbuf[8];
  if (tid==0) lcnt = cnt[j];
  if (tid<128) lnz[tid] = nz[j*128 + tid];
  __syncthreads();
  const int n = lcnt;
  float acc[8] = {0,0,0,0,0,0,0,0};
  for (int e=0; e<n; e++){
    u32 p = lnz[e];
    int k = p >> 16;
    float wv = bf2f((u16)(p & 0xffffu));
    short8 rv = *(const short8*)&S2[(size_t)k*NN + tid*8];
    #pragma unroll
    for (int t=0;t<8;t++) acc[t] = fmaf(bf2f((u16)rv[t]), wv, acc[t]);
  }
  short8 s2v = *(const short8*)&S2[(size_t)j*NN + tid*8];
  short8 o; float k5=0.f,k6=0.f;
  #pragma unroll
  for (int t=0;t<8;t++){
    float a = acc[t], b = bf2f((u16)s2v[t]);
    o[t] = (short)f2bf(a);
    k5 += a*b; k6 += a*a;
  }
  *(short8*)&S3[(size_t)j*NN + tid*8] = o;
  #pragma unroll
  for (int off=32;off>0;off>>=1){ k5 += __shfl_down(k5,off); k6 += __shfl_down(k6,off); }
  if ((tid&63)==0){ int w_ = tid>>6; rbuf[w_]=k5; rbuf[4+w_]=k6; }
  __syncthreads();
  if (tid==0){
    diagsG[j*8+4] = rbuf[0]+rbuf[1]+rbuf[2]+rbuf[3];
    diagsG[j*8+5] = rbuf[4]+rbuf[5]+rbuf[6]+rbuf[7];
  }
}

// LayerNorm(x + sum_{s<nsl} f32 slices) -> xout (f32) and xbf (bf16).
__global__ __launch_bounds__(256)
void ln_kernel(const float* __restrict__ xin, const float* __restrict__ add, int nsl,
               const float* __restrict__ g, const float* __restrict__ b,
               float* __restrict__ xout, u16* __restrict__ xbf)
{
  const int row = blockIdx.x, tid = threadIdx.x;
  __shared__ float red[8];
  const size_t base = (size_t)row*DM;
  float v0 = xin[base+tid];
  float v1 = xin[base+256+tid];
  for (int s=0;s<nsl;s++){
    v0 += add[(size_t)s*NN*DM + base+tid];
    v1 += add[(size_t)s*NN*DM + base+256+tid];
  }
  float s = v0+v1, sq = v0*v0 + v1*v1;
  #pragma unroll
  for (int off=32; off>0; off>>=1){ s += __shfl_down(s, off); sq += __shfl_down(sq, off); }
  if ((tid&63)==0){ red[tid>>6] = s; red[4+(tid>>6)] = sq; }
  __syncthreads();
  float mean = (red[0]+red[1]+red[2]+red[3]) * (1.f/512.f);
  float var  = (red[4]+red[5]+red[6]+red[7]) * (1.f/512.f) - mean*mean;
  float rstd = rsqrtf(var + 1e-5f);
  float y0 = (v0-mean)*rstd*g[tid]     + b[tid];
  float y1 = (v1-mean)*rstd*g[256+tid] + b[256+tid];
  xout[base+tid] = y0;     xout[base+256+tid] = y1;
  xbf[base+tid]  = f2bf(y0); xbf[base+256+tid] = f2bf(y1);
}

// ------- 32x64-tile GEMM body, BK=64, dbuf, XOR-swizzled LDS -------
// OUTMODE: 0 f32, 1 bf16, 2 f32 per-z slice. BIAS: 0 none, 1 col, 2 row.
// ACOMB=1: A-tile built in-regs from 4 attn key-split partials x 1/L.
template<int OUTMODE, int GELU, int BIAS, int ACOMB>
__device__ __forceinline__ void gemm32_body(
    u16* As, u16* Bs, float* invLs,
    const u16* __restrict__ A, const u16* __restrict__ BT,
    const float* __restrict__ bias, void* __restrict__ Cout,
    const u16* __restrict__ Opart, const float* __restrict__ Lsum,
    int M, int N, int K, int ldc, int kper, int bm, int bn, int bz)
{
  const int tid = threadIdx.x, lane = tid & 63, wave = tid >> 6;
  const int q = lane >> 4, lo = lane & 15;
  const int wm = wave >> 1, wn = wave & 1;
  const int k_begin = bz * kper;
  const int kiters = kper >> 6;
  const int srow   = lane >> 3;
  const int gchunk = (lane & 7) ^ srow;

  const u16* Bg = BT + ((size_t)bn*64 + 16*wave + srow) * (size_t)K + k_begin + gchunk*8;
  const size_t r8 = (size_t)8 * K;
  const int Bwoff = wave * 1024;

  const u16* Ag = nullptr;
  const int Awoff = wave * 512;
  if (!ACOMB)
    Ag = A + ((size_t)bm*32 + wave*8 + srow) * (size_t)K + k_begin + gchunk*8;

  int c_sr=0, c_gc=0, c_qb=0, c_rr=0;
  if (ACOMB){
    c_sr = tid >> 3; c_gc = tid & 7;
    c_qb = bm >> 2; c_rr = (bm & 3)*32 + c_sr;
    int hh = tid & 7, rr2 = (bm & 3)*32 + (tid >> 3);
    float L = 0.f;
    #pragma unroll
    for (int ks=0;ks<4;ks++)
      L += Lsum[(((ks*NH + hh)*16 + c_qb))*128 + rr2];
    invLs[(tid>>3)*8 + hh] = 1.f / L;
    __syncthreads();
  }

  float4v acc[2] = {};

  if (ACOMB){
    const int h0 = bz * kiters;
    float a8[8] = {0,0,0,0,0,0,0,0};
    #pragma unroll
    for (int ks=0;ks<4;ks++){
      short8 p = *(const short8*)&Opart[((size_t)((ks*NH + h0)*16 + c_qb))*8192 + c_rr*64 + c_gc*8];
      #pragma unroll
      for (int t=0;t<8;t++) a8[t] += bf2f((u16)p[t]);
    }
    float il = invLs[c_sr*8 + (h0 & 7)];
    short8 o;
    #pragma unroll
    for (int t=0;t<8;t++) o[t] = (short)f2bf_fast(a8[t]*il);
    *(short8*)&As[c_sr*64 + ((c_gc ^ (c_sr&7))*8)] = o;
  } else {
    gl_lds16(Ag, As + Awoff);
  }
  gl_lds16(Bg,      Bs + Bwoff);
  gl_lds16(Bg + r8, Bs + Bwoff + 512);

  for (int it = 0; it < kiters; ++it){
    const int curA = (it & 1) << 11, nxtA = curA ^ 2048;
    const int curB = (it & 1) << 12, nxtB = curB ^ 4096;
    __syncthreads();
    if (it + 1 < kiters){
      const int ko = (it+1)*64;
      if (ACOMB){
        const int h = bz*kiters + it + 1;
        float a8[8] = {0,0,0,0,0,0,0,0};
        #pragma unroll
        for (int ks=0;ks<4;ks++){
          short8 p = *(const short8*)&Opart[((size_t)((ks*NH + h)*16 + c_qb))*8192 + c_rr*64 + c_gc*8];
          #pragma unroll
          for (int t=0;t<8;t++) a8[t] += bf2f((u16)p[t]);
        }
        float il = invLs[c_sr*8 + (h & 7)];
        short8 o;
        #pragma unroll
        for (int t=0;t<8;t++) o[t] = (short)f2bf_fast(a8[t]*il);
        *(short8*)&As[nxtA + c_sr*64 + ((c_gc ^ (c_sr&7))*8)] = o;
      } else {
        gl_lds16(Ag + ko, As + nxtA + Awoff);
      }
      gl_lds16(Bg + ko,      Bs + nxtB + Bwoff);
      gl_lds16(Bg + ko + r8, Bs + nxtB + Bwoff + 512);
    }
    const short8* Ar = (const short8*)(As + curA);
    const short8* Br = (const short8*)(Bs + curB);
    #pragma unroll
    for (int kk=0;kk<2;kk++){
      const int cx = (kk*4 + q) ^ (lo & 7);
      short8 af = Ar[(16*wm + lo)*8 + cx];
      #pragma unroll
      for (int nt=0;nt<2;nt++){
        short8 bfr = Br[(32*wn + 16*nt + lo)*8 + cx];
        acc[nt] = __builtin_amdgcn_mfma_f32_16x16x32_bf16(af, bfr, acc[nt], 0, 0, 0);
      }
    }
  }

  float* Cf = (float*)Cout;
  u16*   Cb = (u16*)Cout;
  const size_t zoff = (OUTMODE == 2) ? (size_t)bz * M * ldc : 0;
  const int row = bm*32 + 16*wm + q*4;
  #pragma unroll
  for (int nt=0;nt<2;nt++){
    const int col = bn*64 + 32*wn + 16*nt + lo;
    float bbc = (BIAS==1) ? bias[col] : 0.f;
    #pragma unroll
    for (int r=0;r<4;r++){
      float v = acc[nt][r];
      float bb = (BIAS==2) ? bias[row+r] : bbc;
      if (OUTMODE == 2){
        if (BIAS && bz == 0) v += bb;
        Cf[zoff + (size_t)(row+r)*ldc + col] = v;
      } else {
        v += bb;
        if (GELU){
          // gelu(x) ~= x * sigmoid(1.5957691x + 0.07135481x^3), err < ~1e-3
          float t2 = v*v;
          float y2 = v*(1.5957691216f + 0.07135481283f*t2);
          v = v / (1.f + exp2f(-1.4426950408889634f*y2));
        }
        if (OUTMODE == 1) Cb[(size_t)(row+r)*ldc + col] = f2bf(v);
        else              Cf[(size_t)(row+r)*ldc + col] = v;
      }
    }
  }
}

template<int OUTMODE, int GELU, int BIAS>
__global__ __launch_bounds__(256)
void gemm32(const u16* __restrict__ A, const u16* __restrict__ BT,
            const float* __restrict__ bias, void* __restrict__ Cout,
            int M, int N, int K, int ldc, int kper)
{
  __shared__ u16 As[2*2048];
  __shared__ u16 Bs[2*4096];
  __shared__ float invLs[256];
  gemm32_body<OUTMODE,GELU,BIAS,0>(As, Bs, invLs, A, BT, bias, Cout, nullptr, nullptr,
                                   M, N, K, ldc, kper, blockIdx.y, blockIdx.x, blockIdx.z);
}

// qk GEMM (1024 tasks) + vT GEMM (512 tasks) in one 1536-block dispatch.
__global__ __launch_bounds__(256)
void qkvt_fused(const u16* __restrict__ xbf, const u16* __restrict__ qkT,
                const float* __restrict__ qkb, u16* __restrict__ qkB,
                const u16* __restrict__ vwT, const float* __restrict__ vb,
                u16* __restrict__ vT)
{
  __shared__ u16 As[2*2048];
  __shared__ u16 Bs[2*4096];
  __shared__ float invLs[256];
  int id = blockIdx.x;
  if (id < 1024)
    gemm32_body<1,0,1,0>(As, Bs, invLs, xbf, qkT, qkb, qkB, nullptr, nullptr,
                         2048, 1024, 512, 1024, 512, id >> 4, id & 15, 0);
  else {
    id -= 1024;
    gemm32_body<1,0,2,0>(As, Bs, invLs, vwT, xbf, vb, vT, nullptr, nullptr,
                         512, 2048, 512, 2048, 512, id >> 5, id & 31, 0);
  }
}

// ------- fused: S4-diag (k7,k8, S4 never materialized) + pe->pebT | qkvt(l0) -------
__global__ __launch_bounds__(256)
void fused_pe_qkvt(const u16* __restrict__ S3, const u32* __restrict__ nz,
                   const int* __restrict__ cnt, const float* __restrict__ diagsG,
                   const float* __restrict__ peW, const float* __restrict__ peb,
                   const float* __restrict__ pebW, const float* __restrict__ pebb,
                   float* __restrict__ pebT,
                   const u16* __restrict__ xbf, const u16* __restrict__ qkT,
                   const float* __restrict__ qkb, u16* __restrict__ qkB,
                   const u16* __restrict__ vwT, const float* __restrict__ vb,
                   u16* __restrict__ vT)
{
  __shared__ __align__(16) char sm[25600];
  int bid = blockIdx.x;
  const int tid = threadIdx.x;
  if (bid < 2048){
    u32*   lnz  = (u32*)sm;            // 128
    int*   lcnt = (int*)(sm + 512);
    float* rbuf = (float*)(sm + 516);  // 8
    float* rrs  = (float*)(sm + 548);  // 8
    float* pv   = (float*)(sm + 580);  // 16
    const int j = bid;
    if (tid==0) *lcnt = cnt[j];
    if (tid<128) lnz[tid] = nz[j*128 + tid];
    __syncthreads();
    const int n = *lcnt;
    float acc[8] = {0,0,0,0,0,0,0,0};
    for (int e=0; e<n; e++){
      u32 p = lnz[e];
      int k = p >> 16;
      float wv = bf2f((u16)(p & 0xffffu));
      short8 rv = *(const short8*)&S3[(size_t)k*NN + tid*8];
      #pragma unroll
      for (int t=0;t<8;t++) acc[t] = fmaf(bf2f((u16)rv[t]), wv, acc[t]);
    }
    short8 s3v = *(const short8*)&S3[(size_t)j*NN + tid*8];
    float k7=0.f,k8=0.f;
    #pragma unroll
    for (int t=0;t<8;t++){
      float a = acc[t], b = bf2f((u16)s3v[t]);
      k7 += a*b; k8 += a*a;
    }
    #pragma unroll
    for (int off=32;off>0;off>>=1){ k7 += __shfl_down(k7,off); k8 += __shfl_down(k8,off); }
    if ((tid&63)==0){ int w_ = tid>>6; rbuf[w_]=k7; rbuf[4+w_]=k8; }
    if (tid<6) rrs[tid] = diagsG[j*8 + tid];
    __syncthreads();
    if (tid==0){
      rrs[6] = rbuf[0]+rbuf[1]+rbuf[2]+rbuf[3];
      rrs[7] = rbuf[4]+rbuf[5]+rbuf[6]+rbuf[7];
    }
    __syncthreads();
    if (tid < 16){
      float a = peb[tid];
      #pragma unroll
      for (int k=0;k<8;k++) a += rrs[k]*peW[k*16 + tid];
      pv[tid] = a;
    }
    __syncthreads();
    if (tid < 24){
      int l = tid >> 3, h = tid & 7;
      float a = pebb[l*NH + h];
      #pragma unroll
      for (int p=0;p<16;p++) a += pv[p]*pebW[(l*16+p)*NH + h];
      pebT[((size_t)l*NH + h)*NN + j] = a;
    }
  } else {
    u16*   As    = (u16*)sm;             // 8 KB
    u16*   Bs    = (u16*)(sm + 8192);    // 16 KB
    float* invLs = (float*)(sm + 24576); // 1 KB
    int id = bid - 2048;
    if (id < 1024)
      gemm32_body<1,0,1,0>(As, Bs, invLs, xbf, qkT, qkb, qkB, nullptr, nullptr,
                           2048, 1024, 512, 1024, 512, id >> 4, id & 15, 0);
    else {
      id -= 1024;
      gemm32_body<1,0,2,0>(As, Bs, invLs, vwT, xbf, vb, vT, nullptr, nullptr,
                           512, 2048, 512, 2048, 512, id >> 5, id & 31, 0);
    }
  }
}

// out-proj with fused attn-combine A-staging. grid (8 n, 64 m, 2 z).
__global__ __launch_bounds__(256)
void outproj_comb(const u16* __restrict__ Opart, const float* __restrict__ Lsum,
                  const u16* __restrict__ outT, const float* __restrict__ outb,
                  float* __restrict__ Cslices)
{
  __shared__ u16 As[2*2048];
  __shared__ u16 Bs[2*4096];
  __shared__ float invLs[256];
  gemm32_body<2,0,1,1>(As, Bs, invLs, nullptr, outT, outb, Cslices, Opart, Lsum,
                       2048, 512, 512, 512, 256, blockIdx.y, blockIdx.x, blockIdx.z);
}

// ------- fused flash attention, Q-tile 128, key-split 4x, dbuf K/V -------
__global__ __launch_bounds__(256)
void attn_part(const u16* __restrict__ qkB, const u16* __restrict__ vT,
               const float* __restrict__ pebT, u16* __restrict__ Opart,
               float* __restrict__ Lsum)
{
  __shared__ u16 Ks[2][64*72];
  __shared__ u16 Vs[2][64*72];
  __shared__ u16 Ps[128*72];
  __shared__ float CB[2][64];
  const int tid = threadIdx.x, lane = tid&63, wave = tid>>6;
  const int q = lane>>4, lo = lane&15;
  const int qb = blockIdx.x, h = blockIdx.y, ks = blockIdx.z;
  const int i0 = qb*128;
  const int part = (ks*NH + h)*16 + qb;

  short8 qf[2][2];
  #pragma unroll
  for (int mt=0;mt<2;mt++)
    #pragma unroll
    for (int kk=0;kk<2;kk++)
      qf[kk][mt] = *(const short8*)&qkB[(size_t)(i0 + 32*wave + 16*mt + lo)*1024 + h*64 + kk*32 + q*8];

  float l_r[2][4] = {};
  float4v o_acc[2][4] = {};

  const int srow = tid >> 2, soff = (tid & 3) * 16;
  const int j_begin = ks*512, j_end = j_begin + 512;

  {
    float4v k0a = *(const float4v*)&qkB[(size_t)(j_begin+srow)*1024 + 512 + h*64 + soff];
    float4v k0b = *(const float4v*)&qkB[(size_t)(j_begin+srow)*1024 + 512 + h*64 + soff + 8];
    float4v v0a = *(const float4v*)&vT[(size_t)(h*64+srow)*NN + j_begin + soff];
    float4v v0b = *(const float4v*)&vT[(size_t)(h*64+srow)*NN + j_begin + soff + 8];
    *(float4v*)&Ks[0][srow*72 + soff]     = k0a;
    *(float4v*)&Ks[0][srow*72 + soff + 8] = k0b;
    *(float4v*)&Vs[0][srow*72 + soff]     = v0a;
    *(float4v*)&Vs[0][srow*72 + soff + 8] = v0b;
    if (tid < 64) CB[0][tid] = pebT[(size_t)h*NN + j_begin + tid] * 1.4426950408889634f;
  }
  __syncthreads();

  for (int j0 = j_begin; j0 < j_end; j0 += 64){
    const int cur = ((j0 - j_begin) >> 6) & 1, nxt = cur ^ 1;
    const bool has_next = (j0 + 64 < j_end);
    float4v ka, kb, va, vb; float cbr = 0.f;
    if (has_next){
      ka = *(const float4v*)&qkB[(size_t)(j0+64+srow)*1024 + 512 + h*64 + soff];
      kb = *(const float4v*)&qkB[(size_t)(j0+64+srow)*1024 + 512 + h*64 + soff + 8];
      va = *(const float4v*)&vT[(size_t)(h*64+srow)*NN + j0+64 + soff];
      vb = *(const float4v*)&vT[(size_t)(h*64+srow)*NN + j0+64 + soff + 8];
      if (tid < 64) cbr = pebT[(size_t)h*NN + j0+64 + tid] * 1.4426950408889634f;
    }

    float4v sacc[2][4] = {};
    const short8* Kr = (const short8*)Ks[cur];
    #pragma unroll
    for (int kk=0; kk<2; kk++){
      #pragma unroll
      for (int nt=0; nt<4; nt++){
        short8 bfr = Kr[(16*nt + lo)*9 + kk*4 + q];
        #pragma unroll
        for (int mt=0; mt<2; mt++)
          sacc[mt][nt] = __builtin_amdgcn_mfma_f32_16x16x32_bf16(qf[kk][mt], bfr, sacc[mt][nt], 0,0,0);
      }
    }
    #pragma unroll
    for (int mt=0; mt<2; mt++)
      #pragma unroll
      for (int nt=0; nt<4; nt++){
        float cb = CB[cur][16*nt + lo];
        #pragma unroll
        for (int r=0;r<4;r++){
          float p = exp2f(fmaf(sacc[mt][nt][r], 0.180336880f, -cb));
          l_r[mt][r] += p;
          Ps[(32*wave + 16*mt + q*4 + r)*72 + 16*nt + lo] = f2bf_fast(p);
        }
      }
    const short8* Pr = (const short8*)Ps;
    const short8* Vr = (const short8*)Vs[cur];
    #pragma unroll
    for (int kk=0;kk<2;kk++){
      #pragma unroll
      for (int mt=0;mt<2;mt++){
        short8 af = Pr[(32*wave + 16*mt + lo)*9 + kk*4 + q];
        #pragma unroll
        for (int nt=0;nt<4;nt++){
          short8 bfr = Vr[(16*nt + lo)*9 + kk*4 + q];
          o_acc[mt][nt] = __builtin_amdgcn_mfma_f32_16x16x32_bf16(af, bfr, o_acc[mt][nt], 0,0,0);
        }
      }
    }
    if (has_next){
      *(float4v*)&Ks[nxt][srow*72 + soff]     = ka;
      *(float4v*)&Ks[nxt][srow*72 + soff + 8] = kb;
      *(float4v*)&Vs[nxt][srow*72 + soff]     = va;
      *(float4v*)&Vs[nxt][srow*72 + soff + 8] = vb;
      if (tid < 64) CB[nxt][tid] = cbr;
    }
    __syncthreads();
  }

  u16* Op = Opart + (size_t)part*8192; // bf16 [128][64]
  #pragma unroll
  for (int mt=0;mt<2;mt++){
    #pragma unroll
    for (int r=0;r<4;r++){
      float s = l_r[mt][r];
      s += __shfl_xor(s, 1);
      s += __shfl_xor(s, 2);
      s += __shfl_xor(s, 4);
      s += __shfl_xor(s, 8);
      if (lo == 0) Lsum[part*128 + 32*wave + 16*mt + q*4 + r] = s;
    }
    #pragma unroll
    for (int nt=0;nt<4;nt++)
      #pragma unroll
      for (int r=0;r<4;r++)
        Op[(32*wave + 16*mt + q*4 + r)*64 + 16*nt + lo] = f2bf_fast(o_acc[mt][nt][r]);
  }
}

// ---------------- launch ----------------
extern "C" void kernel_launch(void* const* d_in, const int* in_sizes, int n_in,
                              void* d_out, int out_size, void* d_ws, size_t ws_size,
                              hipStream_t stream) {
  const float* nf   = (const float*)d_in[0];
  const int*   ei   = (const int*)d_in[1];
  const float* peW  = (const float*)d_in[2];
  const float* peb  = (const float*)d_in[3];
  const float* qkvW = (const float*)d_in[4];
  const float* qkvb = (const float*)d_in[5];
  const float* pebW = (const float*)d_in[6];
  const float* pebb = (const float*)d_in[7];
  const float* outW = (const float*)d_in[8];
  const float* outb = (const float*)d_in[9];
  const float* f1W  = (const float*)d_in[10];
  const float* f1b  = (const float*)d_in[11];
  const float* f2W  = (const float*)d_in[12];
  const float* f2b  = (const float*)d_in[13];
  const float* ln1g = (const float*)d_in[14];
  const float* ln1b = (const float*)d_in[15];
  const float* ln2g = (const float*)d_in[16];
  const float* ln2b = (const float*)d_in[17];
  (void)in_sizes; (void)n_in; (void)out_size; (void)ws_size;

  char* w = (char*)d_ws;
  constexpr size_t OFF_A     = 0;                        // 16.78 MB, reused
  constexpr size_t OFF_S     = OFF_A + 16777216;
  constexpr size_t OFF_S2    = OFF_S + 8388608;
  constexpr size_t OFF_S3    = OFF_S2 + 8388608;
  constexpr size_t OFF_DIAG  = OFF_S3 + 8388608;         // f32 [2048][8]
  constexpr size_t OFF_DINV  = OFF_DIAG + 65536;
  constexpr size_t OFF_PEBT  = OFF_DINV + 8192;
  constexpr size_t OFF_QKVT  = OFF_PEBT + 196608;
  constexpr size_t OFF_OUTT  = OFF_QKVT + 4718592;
  constexpr size_t OFF_F1T   = OFF_OUTT + 1572864;
  constexpr size_t OFF_F2T   = OFF_F1T + 6291456;
  constexpr size_t OFF_X     = OFF_F2T + 6291456;
  constexpr size_t OFF_XBF   = OFF_X + 4194304;
  constexpr size_t OFF_QKB   = OFF_XBF + 2097152;
  constexpr size_t OFF_VT    = OFF_QKB + 4194304;
  constexpr size_t OFF_NZ    = OFF_VT + 2097152;
  constexpr size_t OFF_CNT   = OFF_NZ + 1048576;
  constexpr size_t OFF_LS    = OFF_CNT + 8192;
  constexpr size_t OFF_HBUF  = OFF_LS + 262144;

  float* A     = (float*)(w + OFF_A);
  u16*   S     = (u16*)  (w + OFF_S);
  u16*   S2    = (u16*)  (w + OFF_S2);
  u16*   S3    = (u16*)  (w + OFF_S3);
  float* diagsG= (float*)(w + OFF_DIAG);
  float* dinv  = (float*)(w + OFF_DINV);
  float* pebT  = (float*)(w + OFF_PEBT);
  u16*   qkvT  = (u16*)  (w + OFF_QKVT);
  u16*   outT  = (u16*)  (w + OFF_OUTT);
  u16*   f1T   = (u16*)  (w + OFF_F1T);
  u16*   f2T   = (u16*)  (w + OFF_F2T);
  float* x     = (float*)(w + OFF_X);
  u16*   xbf   = (u16*)  (w + OFF_XBF);
  u16*   qkB   = (u16*)  (w + OFF_QKB);
  u16*   vT    = (u16*)  (w + OFF_VT);
  u32*   NZ    = (u32*)  (w + OFF_NZ);
  int*   CNT   = (int*)  (w + OFF_CNT);
  float* Lsum  = (float*)(w + OFF_LS);
  u16*   hbuf  = (u16*)  (w + OFF_HBUF);
  u16*   Opart   = (u16*)A;                        // 8.4 MB
  float* Oslices = (float*)(w + OFF_A + 8388608);  // 2 x 4.2 MB f32
  float* Fslices = (float*)A;                      // 2 x 4.2 MB f32 (Opart dead)

  // ---- PE path (S sparse: ~33 nnz/row); S4 never materialized ----
  hipMemsetAsync(A, 0, 16777216, stream);
  adj_scatter<<<dim3(NE/256), 256, 0, stream>>>(ei, A);
  rowsum_dinv<<<dim3(NN), 256, 0, stream>>>(A, dinv);
  build_s_nz<<<dim3(NN), 256, 0, stream>>>(A, dinv, S, NZ, CNT);
  // S2+k1..k4 | weight transposes | init_x  (independent, one dispatch)
  fused_prep<<<dim3(15360), 256, 0, stream>>>(NZ, CNT, S, S2, diagsG,
      qkvW, outW, f1W, f2W, qkvT, outT, f1T, f2T, nf, x, xbf);
  spmm_d34<<<dim3(NN), 256, 0, stream>>>(S2, NZ, CNT, S3, diagsG);
  // k7,k8 + pe->pebT | layer-0 qk/vT GEMMs  (independent, one dispatch)
  fused_pe_qkvt<<<dim3(2048 + 1536), 256, 0, stream>>>(S3, NZ, CNT, diagsG,
      peW, peb, pebW, pebb, pebT,
      xbf, qkvT, qkvb, qkB,
      qkvT + (size_t)1024*512, qkvb + 1024, vT);

  // ---- transformer layers ----
  for (int l = 0; l < NL; l++){
    if (l > 0)
      qkvt_fused<<<dim3(1536), 256, 0, stream>>>(
          xbf, qkvT + (size_t)l*1536*512, qkvb + l*1536, qkB,
          qkvT + (size_t)l*1536*512 + (size_t)1024*512, qkvb + l*1536 + 1024, vT);
    attn_part<<<dim3(16,8,4), 256, 0, stream>>>(qkB, vT, pebT + (size_t)l*NH*NN, Opart, Lsum);

    outproj_comb<<<dim3(8,64,2), 256, 0, stream>>>(
        Opart, Lsum, outT + (size_t)l*512*512, outb + l*512, Oslices);
    ln_kernel<<<dim3(NN), 256, 0, stream>>>(x, Oslices, 2, ln1g + l*512, ln1b + l*512, x, xbf);

    gemm32<1,1,1><<<dim3(32,64,1), 256, 0, stream>>>(
        xbf, f1T + (size_t)l*2048*512, f1b + l*2048, hbuf, 2048, 2048, 512, 2048, 512);
    gemm32<2,0,1><<<dim3(8,64,2), 256, 0, stream>>>(
        hbuf, f2T + (size_t)l*512*2048, f2b + l*512, Fslices, 2048, 512, 2048, 512, 1024);
    float* xout = (l == NL-1) ? (float*)d_out : x;
    ln_kernel<<<dim3(NN), 256, 0, stream>>>(x, Fslices, 2, ln2g + l*512, ln2b + l*512, xout, xbf);
  }
}